// Round 1
// baseline (187.550 us; speedup 1.0000x reference)
//
#include <hip/hip_runtime.h>

#define N_NODES 50000
#define N_EDGES 800000
#define D 96
#define D4 (D / 4)        // 24 float4 per row

#define RL 12             // bf16 row = 96*2B = 12 uint4 per node row
#define HPAD 13           // LDS h-row stride in uint4 (kills bank conflicts)
#define CAP 64            // fixed csr slot capacity (u16 entries/node); max in-deg ~45 (Poisson 16)
#define CONV_BLOCKS ((N_NODES * RL + 255) / 256)   // 2344
#define WPREP_BLOCKS ((D * (D / 2) + 255) / 256)   // 18
#define EDGE_BLOCKS ((N_EDGES + 255) / 256)        // 3125

typedef __attribute__((ext_vector_type(8))) short short8;
typedef __attribute__((ext_vector_type(4))) float floatx4;

__device__ __forceinline__ short8 as_short8(uint4 u) { return *(short8*)&u; }

// bf16 RTNE pack: a -> low 16, b -> high 16.
__device__ __forceinline__ unsigned bf16pack(float a, float b) {
    unsigned ua = __float_as_uint(a);
    unsigned ub = __float_as_uint(b);
    ua = (ua + 0x7FFFu + ((ua >> 16) & 1u)) >> 16;       // RTNE
    ub = (ub + 0x7FFFu + ((ub >> 16) & 1u)) & 0xFFFF0000u;
    return ua | ub;
}

// Stage 1: edge-parallel degree count + fixed-slot CSR fill via global atomics.
// deg_out/deg_in zeroed by hipMemsetAsync before this kernel. csr slot order
// within a node is atomic-arrival order (only permutes the fp32 gather sum).
__global__ void __launch_bounds__(256) edge_kernel(
        const int* __restrict__ src, const int* __restrict__ dst,
        int* __restrict__ deg_out, int* __restrict__ deg_in,
        unsigned short* __restrict__ csr) {
    int e = blockIdx.x * 256 + threadIdx.x;
    if (e >= N_EDGES) return;
    int s = src[e];
    int d = dst[e];
    atomicAdd(&deg_out[s], 1);
    int pos = atomicAdd(&deg_in[d], 1);
    if (pos < CAP) csr[(d << 6) + pos] = (unsigned short)s;   // guard: never hit for this graph
}

// Stage 2: sfeat[s] = bf16_rtne(rsqrt(max(out_deg,1)) * feat[s]) (row-major),
// with the W transpose (WT[n][k] = bf16(W[k][n])) folded into the tail blocks.
__global__ void __launch_bounds__(256) conv_kernel(
        const float4* __restrict__ feat4, const int* __restrict__ deg_out,
        uint4* __restrict__ sfeat, const float* __restrict__ W,
        unsigned* __restrict__ WT32) {
    int blk = blockIdx.x;
    if (blk >= CONV_BLOCKS) {   // wprep tail
        int t = (blk - CONV_BLOCKS) * 256 + threadIdx.x;
        if (t >= D * (D / 2)) return;
        int n = t / (D / 2);
        int j = t - n * (D / 2);
        float w0 = W[(2 * j) * D + n];
        float w1 = W[(2 * j + 1) * D + n];
        WT32[n * (D / 2) + j] = bf16pack(w0, w1);
        return;
    }
    int t = blk * 256 + threadIdx.x;
    if (t >= N_NODES * RL) return;
    int n = t / RL;
    int lane = t - n * RL;
    float c = rsqrtf(fmaxf((float)deg_out[n], 1.0f));
    float4 a = feat4[n * D4 + lane * 2];
    float4 b = feat4[n * D4 + lane * 2 + 1];
    uint4 o;
    o.x = bf16pack(a.x * c, a.y * c);
    o.y = bf16pack(a.z * c, a.w * c);
    o.z = bf16pack(b.x * c, b.y * c);
    o.w = bf16pack(b.z * c, b.w * c);
    sfeat[t] = o;
}

// Stage 3 (fused gather+MFMA): one block = one 16-row tile.
// Gather phase: 192 threads (16 nodes x 12 lanes) accumulate h rows into a
// 3.25 KB padded LDS tile. Sync. MFMA phase: 3 waves x 2 col-tiles,
// mfma_f32_16x16x32_bf16, B-frags from L1-resident WT, bias, store fp32.
// Layouts (m89/m91-verified): A[m=lane&15][k=quad*8+j]; B[k=quad*8+j][n=lane&15];
// D col=lane&15, row=quad*4+reg.
__global__ void __launch_bounds__(192) gather_mm_kernel(
        const float4* __restrict__ feat4, const uint4* __restrict__ sfeat,
        const int* __restrict__ deg_in, const unsigned short* __restrict__ csr,
        const uint4* __restrict__ wt4, const float* __restrict__ bias,
        float* __restrict__ out) {
    __shared__ uint4 sh[16 * HPAD];   // 3.25 KB
    int tid = threadIdx.x;
    {   // ---- gather phase ----
        int g = tid / RL;            // node 0..15
        int lane = tid - g * RL;     // uint4 index 0..11 (8 bf16)
        int n = blockIdx.x * 16 + g; // 3125*16 = 50000 exact
        int deg = deg_in[n];
        uint4* __restrict__ hout = &sh[g * HPAD + lane];
        if (deg == 0) {
            float4 a = feat4[n * D4 + lane * 2];
            float4 b = feat4[n * D4 + lane * 2 + 1];
            uint4 o;
            o.x = bf16pack(a.x, a.y);
            o.y = bf16pack(a.z, a.w);
            o.z = bf16pack(b.x, b.y);
            o.w = bf16pack(b.z, b.w);
            *hout = o;
        } else {
            const unsigned short* __restrict__ bk = csr + ((size_t)n << 6);
            const uint4* __restrict__ sf = sfeat + lane;
            int degc = (deg < CAP) ? deg : CAP;   // safety clamp, never hit
            float acc[8] = {};
#define ACC8(v)  { \
        acc[0] += __uint_as_float((v).x << 16); \
        acc[1] += __uint_as_float((v).x & 0xFFFF0000u); \
        acc[2] += __uint_as_float((v).y << 16); \
        acc[3] += __uint_as_float((v).y & 0xFFFF0000u); \
        acc[4] += __uint_as_float((v).z << 16); \
        acc[5] += __uint_as_float((v).z & 0xFFFF0000u); \
        acc[6] += __uint_as_float((v).w << 16); \
        acc[7] += __uint_as_float((v).w & 0xFFFF0000u); }
            int full = degc & ~7;
            int i = 0;
            for (; i < full; i += 8) {
                uint4 idx = *(const uint4*)(bk + i);   // 8 u16 indices (128B-aligned slots)
                unsigned s0 = idx.x & 0xFFFFu, s1 = idx.x >> 16;
                unsigned s2 = idx.y & 0xFFFFu, s3 = idx.y >> 16;
                unsigned s4 = idx.z & 0xFFFFu, s5 = idx.z >> 16;
                unsigned s6 = idx.w & 0xFFFFu, s7 = idx.w >> 16;
                uint4 v0 = sf[(size_t)s0 * RL];
                uint4 v1 = sf[(size_t)s1 * RL];
                uint4 v2 = sf[(size_t)s2 * RL];
                uint4 v3 = sf[(size_t)s3 * RL];
                uint4 v4 = sf[(size_t)s4 * RL];
                uint4 v5 = sf[(size_t)s5 * RL];
                uint4 v6 = sf[(size_t)s6 * RL];
                uint4 v7 = sf[(size_t)s7 * RL];
                ACC8(v0); ACC8(v1); ACC8(v2); ACC8(v3);
                ACC8(v4); ACC8(v5); ACC8(v6); ACC8(v7);
            }
            for (; i < degc; ++i) {
                uint4 v = sf[(size_t)bk[i] * RL];
                ACC8(v);
            }
#undef ACC8
            float cj = rsqrtf((float)deg);
            uint4 o;
            o.x = bf16pack(acc[0] * cj, acc[1] * cj);
            o.y = bf16pack(acc[2] * cj, acc[3] * cj);
            o.z = bf16pack(acc[4] * cj, acc[5] * cj);
            o.w = bf16pack(acc[6] * cj, acc[7] * cj);
            *hout = o;
        }
    }
    __syncthreads();
    // ---- MFMA phase ----
    int wave = tid >> 6;
    int lane = tid & 63;
    int m = lane & 15, quad = lane >> 4;
    short8 a0 = as_short8(sh[m * HPAD + quad]);       // k = 0..31
    short8 a1 = as_short8(sh[m * HPAD + 4 + quad]);   // k = 32..63
    short8 a2 = as_short8(sh[m * HPAD + 8 + quad]);   // k = 64..95
    int row0 = blockIdx.x * 16;
    int r_out0 = row0 + quad * 4;
#pragma unroll
    for (int ct = wave * 2; ct < wave * 2 + 2; ++ct) {
        int n = ct * 16 + m;
        int wb = n * RL + quad;
        short8 b0 = as_short8(wt4[wb]);
        short8 b1 = as_short8(wt4[wb + 4]);
        short8 b2 = as_short8(wt4[wb + 8]);
        floatx4 c = {0.f, 0.f, 0.f, 0.f};
        c = __builtin_amdgcn_mfma_f32_16x16x32_bf16(a0, b0, c, 0, 0, 0);
        c = __builtin_amdgcn_mfma_f32_16x16x32_bf16(a1, b1, c, 0, 0, 0);
        c = __builtin_amdgcn_mfma_f32_16x16x32_bf16(a2, b2, c, 0, 0, 0);
        float bs = bias[n];
#pragma unroll
        for (int r = 0; r < 4; ++r)
            out[(size_t)(r_out0 + r) * D + n] = c[r] + bs;
    }
}

extern "C" void kernel_launch(void* const* d_in, const int* in_sizes, int n_in,
                              void* d_out, int out_size, void* d_ws, size_t ws_size,
                              hipStream_t stream) {
    const float* feat = (const float*)d_in[0];
    const float* W    = (const float*)d_in[1];
    const float* bias = (const float*)d_in[2];
    const int*   src  = (const int*)d_in[3];
    const int*   dst  = (const int*)d_in[4];

    // ws layout (16.42 MB total, every byte rewritten each call or never read):
    //   deg_out[N] | deg_in[N] | csr u16 [N][CAP] 6.4MB | sfeat 9.6MB | WT 18KB
    int*            deg_out = (int*)d_ws;
    int*            deg_in  = deg_out + N_NODES;
    unsigned short* csr     = (unsigned short*)(deg_in + N_NODES);
    uint4*          sfeat   = (uint4*)((char*)csr + (size_t)N_NODES * CAP * 2);
    unsigned*       WT32    = (unsigned*)(sfeat + (size_t)N_NODES * RL);

    hipMemsetAsync(deg_out, 0, 2 * N_NODES * sizeof(int), stream);
    edge_kernel<<<EDGE_BLOCKS, 256, 0, stream>>>(src, dst, deg_out, deg_in, csr);
    conv_kernel<<<CONV_BLOCKS + WPREP_BLOCKS, 256, 0, stream>>>(
        (const float4*)feat, deg_out, sfeat, W, WT32);
    gather_mm_kernel<<<N_NODES / 16, 192, 0, stream>>>(
        (const float4*)feat, sfeat, deg_in, csr, (const uint4*)WT32,
        bias, (float*)d_out);
}

// Round 2
// 159.650 us; speedup vs baseline: 1.1748x; 1.1748x over previous
//
#include <hip/hip_runtime.h>

#define N_NODES 50000
#define N_EDGES 800000
#define D 96
#define D4 (D / 4)        // 24 float4 per row

#define RL 12             // bf16 row = 96*2B = 12 uint4 per node row
#define HPAD 13           // LDS h-row stride in uint4 (kills bank conflicts)
#define CONV_BLOCKS ((N_NODES * RL + 255) / 256)   // 2344
#define WPREP_BLOCKS ((D * (D / 2) + 255) / 256)   // 18

// ---- counting-sort geometry ----
#define NB 196            // buckets of 256 dst nodes (ceil(50000/256))
#define ECAP 5120         // per-bucket edge capacity (mean 4096, +16 sigma)
#define CCAP 6144         // per-bucket padded-CSR capacity u16 (mean ~4990, +16 sigma)
#define PA_BLOCKS 200
#define PA_CHUNK 4000     // 200 * 4000 = 800000 exact

typedef __attribute__((ext_vector_type(8))) short short8;
typedef __attribute__((ext_vector_type(4))) float floatx4;

__device__ __forceinline__ short8 as_short8(uint4 u) { return *(short8*)&u; }

// bf16 RTNE pack: a -> low 16, b -> high 16.
__device__ __forceinline__ unsigned bf16pack(float a, float b) {
    unsigned ua = __float_as_uint(a);
    unsigned ub = __float_as_uint(b);
    ua = (ua + 0x7FFFu + ((ua >> 16) & 1u)) >> 16;       // RTNE
    ub = (ub + 0x7FFFu + ((ub >> 16) & 1u)) & 0xFFFF0000u;
    return ua | ub;
}

// Stage 1a: partition edges into 196 dst-buckets with LDS reorder so global
// writes are contiguous runs (fixes the 69.5 MB partial-line scatter of the
// atomic edge_kernel). Edge packed as (dst<<16)|src — both < 65536.
// deg_out counted via global atomics (50k counters, L2-resident).
__global__ void __launch_bounds__(1024) sortA_kernel(
        const int* __restrict__ src, const int* __restrict__ dst,
        int* __restrict__ deg_out, unsigned* __restrict__ gcur,
        unsigned* __restrict__ ebuf) {
    __shared__ unsigned raw[PA_CHUNK];   // 16.0 KB
    __shared__ unsigned ord[PA_CHUNK];   // 16.0 KB
    __shared__ unsigned hist[NB], lstart[NB], cur[NB], gbase[NB];
    __shared__ unsigned sc[256];
    int t = threadIdx.x;
    int e0 = blockIdx.x * PA_CHUNK;
    for (int i = t; i < NB; i += 1024) hist[i] = 0;
    __syncthreads();
    for (int i = t; i < PA_CHUNK; i += 1024) {
        int s = src[e0 + i];
        int d = dst[e0 + i];
        raw[i] = ((unsigned)d << 16) | (unsigned)s;
        atomicAdd(&deg_out[s], 1);
        atomicAdd(&hist[d >> 8], 1);
    }
    __syncthreads();
    if (t < 256) sc[t] = (t < NB) ? hist[t] : 0;
    __syncthreads();
    for (int o = 1; o < 256; o <<= 1) {      // Hillis-Steele inclusive scan
        unsigned v = 0;
        if (t < 256 && t >= o) v = sc[t - o];
        __syncthreads();
        if (t < 256 && t >= o) sc[t] += v;
        __syncthreads();
    }
    if (t < NB) {
        unsigned ls = sc[t] - hist[t];       // exclusive
        lstart[t] = ls;
        cur[t] = ls;
        gbase[t] = atomicAdd(&gcur[t], hist[t]);
    }
    __syncthreads();
    for (int i = t; i < PA_CHUNK; i += 1024) {   // LDS scatter into bucket order
        unsigned r = raw[i];
        unsigned b = r >> 24;                    // (dst>>8), dst = r>>16 < 50000
        unsigned p = atomicAdd(&cur[b], 1);
        ord[p] = r;
    }
    __syncthreads();
    for (int i = t; i < PA_CHUNK; i += 1024) {   // coalesced-run copy-out
        unsigned r = ord[i];
        unsigned b = r >> 24;
        unsigned pos = gbase[b] + ((unsigned)i - lstart[b]);
        if (pos < ECAP) ebuf[b * ECAP + pos] = r;
    }
}

// Stage 1b: one block per bucket. Per-node counts (-> deg_in, coalesced),
// 8-padded exclusive scan (-> off, 16B-aligned uint4 CSR segments), scatter
// src u16s into an LDS CSR tile, copy out coalesced.
__global__ void __launch_bounds__(1024) sortB_kernel(
        const unsigned* __restrict__ gcur, const unsigned* __restrict__ ebuf,
        int* __restrict__ deg_in, int* __restrict__ off,
        unsigned short* __restrict__ csr) {
    __shared__ unsigned eb[ECAP];              // 20 KB
    __shared__ unsigned short csr_l[CCAP];     // 12 KB
    __shared__ unsigned dcount[256], dcur[256], sc[256];
    int b = blockIdx.x;
    int t = threadIdx.x;
    unsigned cnt = gcur[b];
    if (cnt > ECAP) cnt = ECAP;
    for (int i = t; i < 256; i += 1024) dcount[i] = 0;
    __syncthreads();
    const unsigned* __restrict__ sg = ebuf + (size_t)b * ECAP;
    for (int i = t; i < (int)cnt; i += 1024) {
        unsigned r = sg[i];
        eb[i] = r;
        atomicAdd(&dcount[(r >> 16) & 255u], 1);
    }
    __syncthreads();
    if (t < 256) sc[t] = (dcount[t] + 7u) & ~7u;   // 8-padded sizes
    __syncthreads();
    for (int o = 1; o < 256; o <<= 1) {
        unsigned v = 0;
        if (t < 256 && t >= o) v = sc[t - o];
        __syncthreads();
        if (t < 256 && t >= o) sc[t] += v;
        __syncthreads();
    }
    if (t < 256) {
        int n = b * 256 + t;
        unsigned ex = sc[t] - ((dcount[t] + 7u) & ~7u);   // exclusive padded
        dcur[t] = ex;
        if (n < N_NODES) {
            deg_in[n] = (int)dcount[t];
            off[n] = b * CCAP + (int)ex;
        }
    }
    __syncthreads();
    for (int i = t; i < (int)cnt; i += 1024) {
        unsigned r = eb[i];
        unsigned p = atomicAdd(&dcur[(r >> 16) & 255u], 1);
        if (p < CCAP) csr_l[p] = (unsigned short)(r & 0xFFFFu);
    }
    __syncthreads();
    unsigned tot = sc[255];
    if (tot > CCAP) tot = CCAP;
    unsigned* __restrict__ og = (unsigned*)(csr + (size_t)b * CCAP);
    const unsigned* __restrict__ cl = (const unsigned*)csr_l;
    for (int i = t; i < (int)(tot >> 1); i += 1024) og[i] = cl[i];
}

// Stage 2: sfeat[s] = bf16_rtne(rsqrt(max(out_deg,1)) * feat[s]) (row-major),
// with the W transpose (WT[n][k] = bf16(W[k][n])) folded into the tail blocks.
__global__ void __launch_bounds__(256) conv_kernel(
        const float4* __restrict__ feat4, const int* __restrict__ deg_out,
        uint4* __restrict__ sfeat, const float* __restrict__ W,
        unsigned* __restrict__ WT32) {
    int blk = blockIdx.x;
    if (blk >= CONV_BLOCKS) {   // wprep tail
        int t = (blk - CONV_BLOCKS) * 256 + threadIdx.x;
        if (t >= D * (D / 2)) return;
        int n = t / (D / 2);
        int j = t - n * (D / 2);
        float w0 = W[(2 * j) * D + n];
        float w1 = W[(2 * j + 1) * D + n];
        WT32[n * (D / 2) + j] = bf16pack(w0, w1);
        return;
    }
    int t = blk * 256 + threadIdx.x;
    if (t >= N_NODES * RL) return;
    int n = t / RL;
    int lane = t - n * RL;
    float c = rsqrtf(fmaxf((float)deg_out[n], 1.0f));
    float4 a = feat4[n * D4 + lane * 2];
    float4 b = feat4[n * D4 + lane * 2 + 1];
    uint4 o;
    o.x = bf16pack(a.x * c, a.y * c);
    o.y = bf16pack(a.z * c, a.w * c);
    o.z = bf16pack(b.x * c, b.y * c);
    o.w = bf16pack(b.z * c, b.w * c);
    sfeat[t] = o;
}

// Stage 3 (fused gather+MFMA): one block = one 16-row tile.
// Gather phase: 192 threads (16 nodes x 12 lanes) accumulate h rows into a
// 3.25 KB padded LDS tile. Sync. MFMA phase: 3 waves x 2 col-tiles,
// mfma_f32_16x16x32_bf16, B-frags from L1-resident WT, bias, store fp32.
// Layouts (m89/m91-verified): A[m=lane&15][k=quad*8+j]; B[k=quad*8+j][n=lane&15];
// D col=lane&15, row=quad*4+reg.
__global__ void __launch_bounds__(192) gather_mm_kernel(
        const float4* __restrict__ feat4, const uint4* __restrict__ sfeat,
        const int* __restrict__ deg_in, const int* __restrict__ off,
        const unsigned short* __restrict__ csr, const uint4* __restrict__ wt4,
        const float* __restrict__ bias, float* __restrict__ out) {
    __shared__ uint4 sh[16 * HPAD];   // 3.25 KB
    int tid = threadIdx.x;
    {   // ---- gather phase ----
        int g = tid / RL;            // node 0..15
        int lane = tid - g * RL;     // uint4 index 0..11 (8 bf16)
        int n = blockIdx.x * 16 + g; // 3125*16 = 50000 exact
        int deg = deg_in[n];
        uint4* __restrict__ hout = &sh[g * HPAD + lane];
        if (deg == 0) {
            float4 a = feat4[n * D4 + lane * 2];
            float4 b = feat4[n * D4 + lane * 2 + 1];
            uint4 o;
            o.x = bf16pack(a.x, a.y);
            o.y = bf16pack(a.z, a.w);
            o.z = bf16pack(b.x, b.y);
            o.w = bf16pack(b.z, b.w);
            *hout = o;
        } else {
            const unsigned short* __restrict__ bk = csr + off[n];
            const uint4* __restrict__ sf = sfeat + lane;
            float acc[8] = {};
#define ACC8(v)  { \
        acc[0] += __uint_as_float((v).x << 16); \
        acc[1] += __uint_as_float((v).x & 0xFFFF0000u); \
        acc[2] += __uint_as_float((v).y << 16); \
        acc[3] += __uint_as_float((v).y & 0xFFFF0000u); \
        acc[4] += __uint_as_float((v).z << 16); \
        acc[5] += __uint_as_float((v).z & 0xFFFF0000u); \
        acc[6] += __uint_as_float((v).w << 16); \
        acc[7] += __uint_as_float((v).w & 0xFFFF0000u); }
            int full = deg & ~7;
            int i = 0;
            for (; i < full; i += 8) {
                uint4 idx = *(const uint4*)(bk + i);   // 8 u16 indices (16B-aligned)
                unsigned s0 = idx.x & 0xFFFFu, s1 = idx.x >> 16;
                unsigned s2 = idx.y & 0xFFFFu, s3 = idx.y >> 16;
                unsigned s4 = idx.z & 0xFFFFu, s5 = idx.z >> 16;
                unsigned s6 = idx.w & 0xFFFFu, s7 = idx.w >> 16;
                uint4 v0 = sf[(size_t)s0 * RL];
                uint4 v1 = sf[(size_t)s1 * RL];
                uint4 v2 = sf[(size_t)s2 * RL];
                uint4 v3 = sf[(size_t)s3 * RL];
                uint4 v4 = sf[(size_t)s4 * RL];
                uint4 v5 = sf[(size_t)s5 * RL];
                uint4 v6 = sf[(size_t)s6 * RL];
                uint4 v7 = sf[(size_t)s7 * RL];
                ACC8(v0); ACC8(v1); ACC8(v2); ACC8(v3);
                ACC8(v4); ACC8(v5); ACC8(v6); ACC8(v7);
            }
            for (; i < deg; ++i) {
                uint4 v = sf[(size_t)bk[i] * RL];
                ACC8(v);
            }
#undef ACC8
            float cj = rsqrtf((float)deg);
            uint4 o;
            o.x = bf16pack(acc[0] * cj, acc[1] * cj);
            o.y = bf16pack(acc[2] * cj, acc[3] * cj);
            o.z = bf16pack(acc[4] * cj, acc[5] * cj);
            o.w = bf16pack(acc[6] * cj, acc[7] * cj);
            *hout = o;
        }
    }
    __syncthreads();
    // ---- MFMA phase ----
    int wave = tid >> 6;
    int lane = tid & 63;
    int m = lane & 15, quad = lane >> 4;
    short8 a0 = as_short8(sh[m * HPAD + quad]);       // k = 0..31
    short8 a1 = as_short8(sh[m * HPAD + 4 + quad]);   // k = 32..63
    short8 a2 = as_short8(sh[m * HPAD + 8 + quad]);   // k = 64..95
    int row0 = blockIdx.x * 16;
    int r_out0 = row0 + quad * 4;
#pragma unroll
    for (int ct = wave * 2; ct < wave * 2 + 2; ++ct) {
        int n = ct * 16 + m;
        int wb = n * RL + quad;
        short8 b0 = as_short8(wt4[wb]);
        short8 b1 = as_short8(wt4[wb + 4]);
        short8 b2 = as_short8(wt4[wb + 8]);
        floatx4 c = {0.f, 0.f, 0.f, 0.f};
        c = __builtin_amdgcn_mfma_f32_16x16x32_bf16(a0, b0, c, 0, 0, 0);
        c = __builtin_amdgcn_mfma_f32_16x16x32_bf16(a1, b1, c, 0, 0, 0);
        c = __builtin_amdgcn_mfma_f32_16x16x32_bf16(a2, b2, c, 0, 0, 0);
        float bs = bias[n];
#pragma unroll
        for (int r = 0; r < 4; ++r)
            out[(size_t)(r_out0 + r) * D + n] = c[r] + bs;
    }
}

extern "C" void kernel_launch(void* const* d_in, const int* in_sizes, int n_in,
                              void* d_out, int out_size, void* d_ws, size_t ws_size,
                              hipStream_t stream) {
    const float* feat = (const float*)d_in[0];
    const float* W    = (const float*)d_in[1];
    const float* bias = (const float*)d_in[2];
    const int*   src  = (const int*)d_in[3];
    const int*   dst  = (const int*)d_in[4];

    // ws layout (~16.6 MB; every byte rewritten each call or never read):
    //   deg_out[N] | gcur[NB] | deg_in[N] | off[N] |
    //   ebuf u32 [NB][ECAP] 4.0MB | csr u16 [NB][CCAP] 2.4MB | sfeat 9.6MB | WT 18KB
    int*            deg_out = (int*)d_ws;
    unsigned*       gcur    = (unsigned*)(deg_out + N_NODES);
    int*            deg_in  = (int*)(gcur + NB);
    int*            off     = deg_in + N_NODES;
    unsigned*       ebuf    = (unsigned*)(off + N_NODES);
    unsigned short* csr     = (unsigned short*)(ebuf + (size_t)NB * ECAP);
    uint4*          sfeat   = (uint4*)((char*)csr + (size_t)NB * CCAP * 2);
    unsigned*       WT32    = (unsigned*)(sfeat + (size_t)N_NODES * RL);

    hipMemsetAsync(deg_out, 0, (N_NODES + NB) * sizeof(int), stream);  // deg_out + gcur
    sortA_kernel<<<PA_BLOCKS, 1024, 0, stream>>>(src, dst, deg_out, gcur, ebuf);
    sortB_kernel<<<NB, 1024, 0, stream>>>(gcur, ebuf, deg_in, off, csr);
    conv_kernel<<<CONV_BLOCKS + WPREP_BLOCKS, 256, 0, stream>>>(
        (const float4*)feat, deg_out, sfeat, W, WT32);
    gather_mm_kernel<<<N_NODES / 16, 192, 0, stream>>>(
        (const float4*)feat, sfeat, deg_in, off, csr, (const uint4*)WT32,
        bias, (float*)d_out);
}

// Round 3
// 138.778 us; speedup vs baseline: 1.3514x; 1.1504x over previous
//
#include <hip/hip_runtime.h>

#define N_NODES 50000
#define N_EDGES 800000
#define D 96
#define D4 (D / 4)        // 24 float4 per row

#define RL 12             // bf16 row = 96*2B = 12 uint4 per node row
#define HPAD 13           // LDS h-row stride in uint4 (kills bank conflicts)
#define CONV_BLOCKS ((N_NODES * RL + 255) / 256)   // 2344
#define WPREP_BLOCKS ((D * (D / 2) + 255) / 256)   // 18

// ---- counting-sort geometry ----
#define NB 196            // buckets of 256 nodes (ceil(50000/256))
#define ECAP 5120         // per-bucket dst-edge capacity (mean 4081, +16 sigma)
#define SCAP 5120         // per-bucket src-entry capacity (same stats)
#define CCAP 6144         // per-bucket padded-CSR capacity u16 (mean ~5000, +16 sigma)
#define PA_BLOCKS 256
#define PA_CHUNK 3125     // 256 * 3125 = 800000 exact; one block per CU

typedef __attribute__((ext_vector_type(8))) short short8;
typedef __attribute__((ext_vector_type(4))) float floatx4;

__device__ __forceinline__ short8 as_short8(uint4 u) { return *(short8*)&u; }

// bf16 RTNE pack: a -> low 16, b -> high 16.
__device__ __forceinline__ unsigned bf16pack(float a, float b) {
    unsigned ua = __float_as_uint(a);
    unsigned ub = __float_as_uint(b);
    ua = (ua + 0x7FFFu + ((ua >> 16) & 1u)) >> 16;       // RTNE
    ub = (ub + 0x7FFFu + ((ub >> 16) & 1u)) & 0xFFFF0000u;
    return ua | ub;
}

// Stage 1a: dual-key bucket partition. Edges go to dst-buckets (ebuf, as
// (dst<<16)|src) AND src values go to src-buckets (sbuf, u16) via one LDS
// counting sort with a fused 512-wide dual scan. NO global data atomics —
// deg_out is derived from sbuf in sortB (this removes the 800k device-scope
// atomicAdd stream, the prime suspect for the 55us build stage).
__global__ void __launch_bounds__(1024) sortA_kernel(
        const int* __restrict__ src, const int* __restrict__ dst,
        unsigned* __restrict__ gcur,       // [2*NB]: dst cursors | src cursors
        unsigned* __restrict__ ebuf, unsigned short* __restrict__ sbuf) {
    __shared__ unsigned raw[PA_CHUNK];          // 12.5 KB
    __shared__ unsigned ord[PA_CHUNK];          // 12.5 KB
    __shared__ unsigned short sord[PA_CHUNK];   // 6.25 KB
    __shared__ unsigned hist[512];   // [0..255] dst-buckets, [256..511] src-buckets
    __shared__ unsigned sc[512], lstart[512], cur[512], gbase[512];
    int t = threadIdx.x;
    int e0 = blockIdx.x * PA_CHUNK;
    if (t < 512) hist[t] = 0;
    __syncthreads();
    for (int i = t; i < PA_CHUNK; i += 1024) {
        int s = src[e0 + i];
        int d = dst[e0 + i];
        raw[i] = ((unsigned)d << 16) | (unsigned)s;
        atomicAdd(&hist[d >> 8], 1u);
        atomicAdd(&hist[256 + (s >> 8)], 1u);
    }
    __syncthreads();
    if (t < 512) sc[t] = hist[t];
    __syncthreads();
    for (int o = 1; o < 256; o <<= 1) {      // two Hillis-Steele scans, fused
        unsigned v = 0;
        if (t < 512 && (t & 255) >= o) v = sc[t - o];
        __syncthreads();
        if (t < 512 && (t & 255) >= o) sc[t] += v;
        __syncthreads();
    }
    if (t < 512) {
        unsigned ls = sc[t] - hist[t];       // exclusive
        lstart[t] = ls;
        cur[t] = ls;
        if ((t & 255) < NB)
            gbase[t] = atomicAdd(&gcur[(t >> 8) * NB + (t & 255)], hist[t]);
    }
    __syncthreads();
    for (int i = t; i < PA_CHUNK; i += 1024) {   // LDS scatter into bucket order
        unsigned r = raw[i];
        unsigned p = atomicAdd(&cur[r >> 24], 1u);        // dst bucket
        ord[p] = r;
        unsigned s = r & 0xFFFFu;
        unsigned q = atomicAdd(&cur[256 + (s >> 8)], 1u); // src bucket
        sord[q] = (unsigned short)s;
    }
    __syncthreads();
    for (int i = t; i < PA_CHUNK; i += 1024) {   // coalesced-run copy-out
        unsigned r = ord[i];
        unsigned bd = r >> 24;
        unsigned pos = gbase[bd] + ((unsigned)i - lstart[bd]);
        if (pos < ECAP) ebuf[bd * ECAP + pos] = r;
        unsigned s = sord[i];
        unsigned bs = 256 + (s >> 8);
        unsigned pos2 = gbase[bs] + ((unsigned)i - lstart[bs]);
        if (pos2 < SCAP) sbuf[(size_t)(bs - 256) * SCAP + pos2] = (unsigned short)s;
    }
}

// Stage 1b: one block per bucket (256 owned nodes). Per-node dst counts
// (-> deg_in) AND src counts from sbuf (-> deg_out), both written coalesced.
// 8-padded exclusive scan -> off (16B-aligned uint4 CSR segments), scatter
// src u16s into an LDS CSR tile, copy out coalesced.
__global__ void __launch_bounds__(1024) sortB_kernel(
        const unsigned* __restrict__ gcur, const unsigned* __restrict__ ebuf,
        const unsigned short* __restrict__ sbuf,
        int* __restrict__ deg_out, int* __restrict__ deg_in,
        int* __restrict__ off, unsigned short* __restrict__ csr) {
    __shared__ unsigned eb[ECAP];              // 20 KB
    __shared__ unsigned short csr_l[CCAP];     // 12 KB
    __shared__ unsigned dcount[256], dcur[256], scount[256], sc[256];
    int b = blockIdx.x;
    int t = threadIdx.x;
    unsigned cntd = gcur[b];      if (cntd > ECAP) cntd = ECAP;
    unsigned cnts = gcur[NB + b]; if (cnts > SCAP) cnts = SCAP;
    if (t < 256) { dcount[t] = 0; scount[t] = 0; }
    __syncthreads();
    const unsigned* __restrict__ sg = ebuf + (size_t)b * ECAP;
    for (int i = t; i < (int)cntd; i += 1024) {
        unsigned r = sg[i];
        eb[i] = r;
        atomicAdd(&dcount[(r >> 16) & 255u], 1u);
    }
    const unsigned short* __restrict__ ss = sbuf + (size_t)b * SCAP;
    for (int i = t; i < (int)cnts; i += 1024)
        atomicAdd(&scount[ss[i] & 255u], 1u);
    __syncthreads();
    if (t < 256) sc[t] = (dcount[t] + 7u) & ~7u;   // 8-padded sizes
    __syncthreads();
    for (int o = 1; o < 256; o <<= 1) {
        unsigned v = 0;
        if (t < 256 && t >= o) v = sc[t - o];
        __syncthreads();
        if (t < 256 && t >= o) sc[t] += v;
        __syncthreads();
    }
    if (t < 256) {
        int n = b * 256 + t;
        unsigned ex = sc[t] - ((dcount[t] + 7u) & ~7u);   // exclusive padded
        dcur[t] = ex;
        if (n < N_NODES) {
            deg_in[n]  = (int)dcount[t];
            deg_out[n] = (int)scount[t];
            off[n] = b * CCAP + (int)ex;
        }
    }
    __syncthreads();
    for (int i = t; i < (int)cntd; i += 1024) {
        unsigned r = eb[i];
        unsigned p = atomicAdd(&dcur[(r >> 16) & 255u], 1u);
        if (p < CCAP) csr_l[p] = (unsigned short)(r & 0xFFFFu);
    }
    __syncthreads();
    unsigned tot = sc[255];
    if (tot > CCAP) tot = CCAP;
    unsigned* __restrict__ og = (unsigned*)(csr + (size_t)b * CCAP);
    const unsigned* __restrict__ cl = (const unsigned*)csr_l;
    for (int i = t; i < (int)(tot >> 1); i += 1024) og[i] = cl[i];
}

// Stage 2: sfeat[s] = bf16_rtne(rsqrt(max(out_deg,1)) * feat[s]) (row-major),
// with the W transpose (WT[n][k] = bf16(W[k][n])) folded into the tail blocks.
__global__ void __launch_bounds__(256) conv_kernel(
        const float4* __restrict__ feat4, const int* __restrict__ deg_out,
        uint4* __restrict__ sfeat, const float* __restrict__ W,
        unsigned* __restrict__ WT32) {
    int blk = blockIdx.x;
    if (blk >= CONV_BLOCKS) {   // wprep tail
        int t = (blk - CONV_BLOCKS) * 256 + threadIdx.x;
        if (t >= D * (D / 2)) return;
        int n = t / (D / 2);
        int j = t - n * (D / 2);
        float w0 = W[(2 * j) * D + n];
        float w1 = W[(2 * j + 1) * D + n];
        WT32[n * (D / 2) + j] = bf16pack(w0, w1);
        return;
    }
    int t = blk * 256 + threadIdx.x;
    if (t >= N_NODES * RL) return;
    int n = t / RL;
    int lane = t - n * RL;
    float c = rsqrtf(fmaxf((float)deg_out[n], 1.0f));
    float4 a = feat4[n * D4 + lane * 2];
    float4 b = feat4[n * D4 + lane * 2 + 1];
    uint4 o;
    o.x = bf16pack(a.x * c, a.y * c);
    o.y = bf16pack(a.z * c, a.w * c);
    o.z = bf16pack(b.x * c, b.y * c);
    o.w = bf16pack(b.z * c, b.w * c);
    sfeat[t] = o;
}

// Stage 3 (fused gather+MFMA): one block = one 16-row tile.
// Gather phase: 192 threads (16 nodes x 12 lanes), 16-deep row prefetch
// (2 idx uint4s up front, 16 independent row loads in flight) to maximize
// MLP — the phase is L2/L3-latency-bound, not BW-bound. Sync. MFMA phase:
// 3 waves x 2 col-tiles, mfma_f32_16x16x32_bf16, bias, store fp32.
// Layouts (m89/m91-verified): A[m=lane&15][k=quad*8+j]; B[k=quad*8+j][n=lane&15];
// D col=lane&15, row=quad*4+reg.
__global__ void __launch_bounds__(192) gather_mm_kernel(
        const float4* __restrict__ feat4, const uint4* __restrict__ sfeat,
        const int* __restrict__ deg_in, const int* __restrict__ off,
        const unsigned short* __restrict__ csr, const uint4* __restrict__ wt4,
        const float* __restrict__ bias, float* __restrict__ out) {
    __shared__ uint4 sh[16 * HPAD];   // 3.25 KB
    int tid = threadIdx.x;
    {   // ---- gather phase ----
        int g = tid / RL;            // node 0..15
        int lane = tid - g * RL;     // uint4 index 0..11 (8 bf16)
        int n = blockIdx.x * 16 + g; // 3125*16 = 50000 exact
        int deg = deg_in[n];
        uint4* __restrict__ hout = &sh[g * HPAD + lane];
        if (deg == 0) {
            float4 a = feat4[n * D4 + lane * 2];
            float4 b = feat4[n * D4 + lane * 2 + 1];
            uint4 o;
            o.x = bf16pack(a.x, a.y);
            o.y = bf16pack(a.z, a.w);
            o.z = bf16pack(b.x, b.y);
            o.w = bf16pack(b.z, b.w);
            *hout = o;
        } else {
            const unsigned short* __restrict__ bk = csr + off[n];
            const uint4* __restrict__ sf = sfeat + lane;
            float acc[8] = {};
#define ACC8(v)  { \
        acc[0] += __uint_as_float((v).x << 16); \
        acc[1] += __uint_as_float((v).x & 0xFFFF0000u); \
        acc[2] += __uint_as_float((v).y << 16); \
        acc[3] += __uint_as_float((v).y & 0xFFFF0000u); \
        acc[4] += __uint_as_float((v).z << 16); \
        acc[5] += __uint_as_float((v).z & 0xFFFF0000u); \
        acc[6] += __uint_as_float((v).w << 16); \
        acc[7] += __uint_as_float((v).w & 0xFFFF0000u); }
            int i = 0;
            int full16 = deg & ~15;
            for (; i < full16; i += 16) {
                uint4 ia = *(const uint4*)(bk + i);       // 8 u16 indices
                uint4 ib = *(const uint4*)(bk + i + 8);   // 8 more
                unsigned s0 = ia.x & 0xFFFFu, s1 = ia.x >> 16;
                unsigned s2 = ia.y & 0xFFFFu, s3 = ia.y >> 16;
                unsigned s4 = ia.z & 0xFFFFu, s5 = ia.z >> 16;
                unsigned s6 = ia.w & 0xFFFFu, s7 = ia.w >> 16;
                unsigned s8 = ib.x & 0xFFFFu, s9 = ib.x >> 16;
                unsigned sa = ib.y & 0xFFFFu, sb = ib.y >> 16;
                unsigned sx = ib.z & 0xFFFFu, sd = ib.z >> 16;
                unsigned se = ib.w & 0xFFFFu, sfi = ib.w >> 16;
                uint4 v0 = sf[(size_t)s0 * RL];
                uint4 v1 = sf[(size_t)s1 * RL];
                uint4 v2 = sf[(size_t)s2 * RL];
                uint4 v3 = sf[(size_t)s3 * RL];
                uint4 v4 = sf[(size_t)s4 * RL];
                uint4 v5 = sf[(size_t)s5 * RL];
                uint4 v6 = sf[(size_t)s6 * RL];
                uint4 v7 = sf[(size_t)s7 * RL];
                uint4 v8 = sf[(size_t)s8 * RL];
                uint4 v9 = sf[(size_t)s9 * RL];
                uint4 va = sf[(size_t)sa * RL];
                uint4 vb = sf[(size_t)sb * RL];
                uint4 vc = sf[(size_t)sx * RL];
                uint4 vd = sf[(size_t)sd * RL];
                uint4 ve = sf[(size_t)se * RL];
                uint4 vf = sf[(size_t)sfi * RL];
                ACC8(v0); ACC8(v1); ACC8(v2); ACC8(v3);
                ACC8(v4); ACC8(v5); ACC8(v6); ACC8(v7);
                ACC8(v8); ACC8(v9); ACC8(va); ACC8(vb);
                ACC8(vc); ACC8(vd); ACC8(ve); ACC8(vf);
            }
            int full8 = deg & ~7;
            for (; i < full8; i += 8) {
                uint4 idx = *(const uint4*)(bk + i);
                unsigned s0 = idx.x & 0xFFFFu, s1 = idx.x >> 16;
                unsigned s2 = idx.y & 0xFFFFu, s3 = idx.y >> 16;
                unsigned s4 = idx.z & 0xFFFFu, s5 = idx.z >> 16;
                unsigned s6 = idx.w & 0xFFFFu, s7 = idx.w >> 16;
                uint4 v0 = sf[(size_t)s0 * RL];
                uint4 v1 = sf[(size_t)s1 * RL];
                uint4 v2 = sf[(size_t)s2 * RL];
                uint4 v3 = sf[(size_t)s3 * RL];
                uint4 v4 = sf[(size_t)s4 * RL];
                uint4 v5 = sf[(size_t)s5 * RL];
                uint4 v6 = sf[(size_t)s6 * RL];
                uint4 v7 = sf[(size_t)s7 * RL];
                ACC8(v0); ACC8(v1); ACC8(v2); ACC8(v3);
                ACC8(v4); ACC8(v5); ACC8(v6); ACC8(v7);
            }
            for (; i < deg; ++i) {
                uint4 v = sf[(size_t)bk[i] * RL];
                ACC8(v);
            }
#undef ACC8
            float cj = rsqrtf((float)deg);
            uint4 o;
            o.x = bf16pack(acc[0] * cj, acc[1] * cj);
            o.y = bf16pack(acc[2] * cj, acc[3] * cj);
            o.z = bf16pack(acc[4] * cj, acc[5] * cj);
            o.w = bf16pack(acc[6] * cj, acc[7] * cj);
            *hout = o;
        }
    }
    __syncthreads();
    // ---- MFMA phase ----
    int wave = tid >> 6;
    int lane = tid & 63;
    int m = lane & 15, quad = lane >> 4;
    short8 a0 = as_short8(sh[m * HPAD + quad]);       // k = 0..31
    short8 a1 = as_short8(sh[m * HPAD + 4 + quad]);   // k = 32..63
    short8 a2 = as_short8(sh[m * HPAD + 8 + quad]);   // k = 64..95
    int row0 = blockIdx.x * 16;
    int r_out0 = row0 + quad * 4;
#pragma unroll
    for (int ct = wave * 2; ct < wave * 2 + 2; ++ct) {
        int n = ct * 16 + m;
        int wb = n * RL + quad;
        short8 b0 = as_short8(wt4[wb]);
        short8 b1 = as_short8(wt4[wb + 4]);
        short8 b2 = as_short8(wt4[wb + 8]);
        floatx4 c = {0.f, 0.f, 0.f, 0.f};
        c = __builtin_amdgcn_mfma_f32_16x16x32_bf16(a0, b0, c, 0, 0, 0);
        c = __builtin_amdgcn_mfma_f32_16x16x32_bf16(a1, b1, c, 0, 0, 0);
        c = __builtin_amdgcn_mfma_f32_16x16x32_bf16(a2, b2, c, 0, 0, 0);
        float bs = bias[n];
#pragma unroll
        for (int r = 0; r < 4; ++r)
            out[(size_t)(r_out0 + r) * D + n] = c[r] + bs;
    }
}

extern "C" void kernel_launch(void* const* d_in, const int* in_sizes, int n_in,
                              void* d_out, int out_size, void* d_ws, size_t ws_size,
                              hipStream_t stream) {
    const float* feat = (const float*)d_in[0];
    const float* W    = (const float*)d_in[1];
    const float* bias = (const float*)d_in[2];
    const int*   src  = (const int*)d_in[3];
    const int*   dst  = (const int*)d_in[4];

    // ws layout (~19.3 MB; every byte rewritten each call or never read):
    //   gcur[2*NB] | deg_out[N] | deg_in[N] | off[N] |
    //   ebuf u32 [NB][ECAP] 4.0MB | sbuf u16 [NB][SCAP] 2.0MB |
    //   csr u16 [NB][CCAP] 2.4MB | sfeat 9.6MB | WT 18KB
    unsigned*       gcur    = (unsigned*)d_ws;
    int*            deg_out = (int*)(gcur + 2 * NB);
    int*            deg_in  = deg_out + N_NODES;
    int*            off     = deg_in + N_NODES;
    unsigned*       ebuf    = (unsigned*)(off + N_NODES);
    unsigned short* sbuf    = (unsigned short*)(ebuf + (size_t)NB * ECAP);
    unsigned short* csr     = sbuf + (size_t)NB * SCAP;
    uint4*          sfeat   = (uint4*)(csr + (size_t)NB * CCAP);
    unsigned*       WT32    = (unsigned*)(sfeat + (size_t)N_NODES * RL);

    hipMemsetAsync(gcur, 0, 2 * NB * sizeof(unsigned), stream);
    sortA_kernel<<<PA_BLOCKS, 1024, 0, stream>>>(src, dst, gcur, ebuf, sbuf);
    sortB_kernel<<<NB, 1024, 0, stream>>>(gcur, ebuf, sbuf, deg_out, deg_in, off, csr);
    conv_kernel<<<CONV_BLOCKS + WPREP_BLOCKS, 256, 0, stream>>>(
        (const float4*)feat, deg_out, sfeat, W, WT32);
    gather_mm_kernel<<<N_NODES / 16, 192, 0, stream>>>(
        (const float4*)feat, sfeat, deg_in, off, csr, (const uint4*)WT32,
        bias, (float*)d_out);
}